// Round 1
// baseline (7768.887 us; speedup 1.0000x reference)
//
#include <hip/hip_runtime.h>
#include <math.h>

// Problem constants (from reference)
constexpr int Bv  = 4;
constexpr int Lv  = 2048;
constexpr int DM  = 258;            // d_model
constexpr int NL  = 4;              // layers
constexpr int DS  = 16;             // d_state
constexpr int DC  = 4;              // d_conv
constexpr int DI  = 516;            // d_inner
constexpr int DTR = 17;             // dt_rank
constexpr int XDBL = DTR + 2*DS;    // 49
constexpr int TOK = Bv*Lv;          // 8192
constexpr float EPS = 1e-5f;

// ---------------- elementwise copy ----------------
__global__ void copy_kernel(float* __restrict__ dst, const float* __restrict__ src, int n) {
    int i = blockIdx.x*256 + threadIdx.x;
    if (i < n) dst[i] = src[i];
}

// ---------------- rmsnorm: one block (256 thr) per token ----------------
__global__ void rmsnorm_kernel(float* __restrict__ out, const float* __restrict__ x,
                               const float* __restrict__ w) {
    int tok = blockIdx.x;
    const float* xr = x + (size_t)tok*DM;
    int t = threadIdx.x;
    float v0 = xr[t];
    float v1 = (t < DM-256) ? xr[256+t] : 0.f;
    float ss = v0*v0 + v1*v1;
    for (int o = 32; o; o >>= 1) ss += __shfl_down(ss, o, 64);
    __shared__ float red[4];
    int wid = t >> 6, lane = t & 63;
    if (lane == 0) red[wid] = ss;
    __syncthreads();
    float tot = red[0]+red[1]+red[2]+red[3];
    float r = rsqrtf(tot/(float)DM + EPS);
    float* outr = out + (size_t)tok*DM;
    outr[t] = v0*r*w[t];
    if (t < DM-256) outr[256+t] = v1*r*w[256+t];
}

// ---------------- final: out = fuse + rmsnorm(x, w) ----------------
__global__ void final_kernel(float* __restrict__ out, const float* __restrict__ x,
                             const float* __restrict__ fuse, const float* __restrict__ w) {
    int tok = blockIdx.x;
    const float* xr = x + (size_t)tok*DM;
    const float* fr = fuse + (size_t)tok*DM;
    int t = threadIdx.x;
    float v0 = xr[t];
    float v1 = (t < DM-256) ? xr[256+t] : 0.f;
    float ss = v0*v0 + v1*v1;
    for (int o = 32; o; o >>= 1) ss += __shfl_down(ss, o, 64);
    __shared__ float red[4];
    int wid = t >> 6, lane = t & 63;
    if (lane == 0) red[wid] = ss;
    __syncthreads();
    float tot = red[0]+red[1]+red[2]+red[3];
    float r = rsqrtf(tot/(float)DM + EPS);
    float* outr = out + (size_t)tok*DM;
    outr[t] = fr[t] + v0*r*w[t];
    if (t < DM-256) outr[256+t] = fr[256+t] + v1*r*w[256+t];
}

// ---------------- NT GEMM: C[M,N] = A[M,K] * Bw[N,K]^T (+resid) ----------------
// 64x64 tile, BK=16, 256 threads, 4x4 outputs/thread
__global__ __launch_bounds__(256) void gemm_nt64(
    const float* __restrict__ A, const float* __restrict__ Bw,
    const float* __restrict__ resid, float* __restrict__ C,
    int M, int N, int K) {
    __shared__ float As[64][17];
    __shared__ float Bs[64][17];
    int tid = threadIdx.x;
    int tx = tid & 15, ty = tid >> 4;
    int row0 = blockIdx.y * 64, col0 = blockIdx.x * 64;
    float acc[4][4] = {};
    for (int k0 = 0; k0 < K; k0 += 16) {
        for (int i = 0; i < 4; i++) {
            int e = tid + i*256;
            int m = e >> 4, k = e & 15;
            int gk = k0 + k;
            int gm = row0 + m;
            As[m][k] = (gm < M && gk < K) ? A[(size_t)gm*K + gk] : 0.f;
            int gn = col0 + m;
            Bs[m][k] = (gn < N && gk < K) ? Bw[(size_t)gn*K + gk] : 0.f;
        }
        __syncthreads();
        int kmax = (K - k0 < 16) ? (K - k0) : 16;
        for (int kk = 0; kk < kmax; kk++) {
            float a[4], b[4];
            #pragma unroll
            for (int i = 0; i < 4; i++) a[i] = As[ty*4+i][kk];
            #pragma unroll
            for (int j = 0; j < 4; j++) b[j] = Bs[tx*4+j][kk];
            #pragma unroll
            for (int i = 0; i < 4; i++)
                #pragma unroll
                for (int j = 0; j < 4; j++)
                    acc[i][j] += a[i]*b[j];
        }
        __syncthreads();
    }
    for (int i = 0; i < 4; i++) {
        int gm = row0 + ty*4 + i;
        if (gm >= M) continue;
        for (int j = 0; j < 4; j++) {
            int gn = col0 + tx*4 + j;
            if (gn >= N) continue;
            float v = acc[i][j];
            if (resid) v += resid[(size_t)gm*N + gn];
            C[(size_t)gm*N + gn] = v;
        }
    }
}

// ---------------- causal depthwise conv (k=4) + silu ----------------
// xi[tok,d] = silu(cb[d] + sum_j xz[tok-3+j, d] * cw[d,j])   (xi half of xz)
__global__ void conv_silu_kernel(float* __restrict__ xi, const float* __restrict__ xz,
                                 const float* __restrict__ cw, const float* __restrict__ cb) {
    int idx = blockIdx.x*256 + threadIdx.x;
    if (idx >= TOK*DI) return;
    int d = idx % DI, tok = idx / DI;
    int l = tok % Lv;
    float acc = cb[d];
    #pragma unroll
    for (int j = 0; j < DC; j++) {
        int lj = l - (DC-1) + j;
        if (lj >= 0)
            acc += xz[(size_t)(tok - (DC-1) + j)*(2*DI) + d] * cw[d*DC + j];
    }
    xi[idx] = acc / (1.f + __expf(-acc));   // silu
}

// ---------------- dt = softplus(dt_lo @ dtw^T + dtb) ----------------
__global__ void dt_kernel(float* __restrict__ dt, const float* __restrict__ xdbl,
                          const float* __restrict__ dtw, const float* __restrict__ dtb) {
    int idx = blockIdx.x*256 + threadIdx.x;
    if (idx >= TOK*DI) return;
    int d = idx % DI, tok = idx / DI;
    const float* xr = xdbl + (size_t)tok*XDBL;
    float acc = dtb[d];
    #pragma unroll
    for (int r = 0; r < DTR; r++) acc += xr[r] * dtw[d*DTR + r];
    dt[idx] = fmaxf(acc, 0.f) + log1pf(__expf(-fabsf(acc)));
}

// ---------------- selective scan: 16 lanes (one per state) per channel ----------------
// grid = B*DI/16 = 129 blocks of 256 (16 channels/block)
__global__ void scan_kernel(float* __restrict__ y, const float* __restrict__ dt,
                            const float* __restrict__ xi, const float* __restrict__ xdbl,
                            const float* __restrict__ xz, const float* __restrict__ A_log,
                            const float* __restrict__ Dp) {
    int tid = threadIdx.x;
    int s = tid & (DS-1);
    int c = blockIdx.x * 16 + (tid >> 4);   // channel index in [0, B*DI)
    int b = c / DI, d = c % DI;
    float a = -__expf(A_log[d*DS + s]);
    float Dv = Dp[d];
    float h = 0.f;
    for (int t = 0; t < Lv; t++) {
        size_t tok = (size_t)b*Lv + t;
        float dtv = dt[tok*DI + d];
        float u   = xi[tok*DI + d];
        float Bvv = xdbl[tok*XDBL + DTR + s];
        float Cv  = xdbl[tok*XDBL + DTR + DS + s];
        float dA = __expf(dtv * a);
        h = dA*h + (dtv*u)*Bvv;
        float p = h*Cv;
        p += __shfl_xor(p, 8, 16);
        p += __shfl_xor(p, 4, 16);
        p += __shfl_xor(p, 2, 16);
        p += __shfl_xor(p, 1, 16);
        if (s == 0) {
            float yv = p + u*Dv;
            float zv = xz[tok*(2*DI) + DI + d];
            y[tok*DI + d] = yv * (zv / (1.f + __expf(-zv)));
        }
    }
}

extern "C" void kernel_launch(void* const* d_in, const int* in_sizes, int n_in,
                              void* d_out, int out_size, void* d_ws, size_t ws_size,
                              hipStream_t stream) {
    const float* fuse   = (const float*)d_in[0];
    const float* norm_w = (const float*)d_in[1];
    const float* in_w   = (const float*)d_in[2];
    const float* conv_w = (const float*)d_in[3];
    const float* conv_b = (const float*)d_in[4];
    const float* xp_w   = (const float*)d_in[5];
    const float* dt_w   = (const float*)d_in[6];
    const float* dt_b   = (const float*)d_in[7];
    const float* A_log  = (const float*)d_in[8];
    const float* D_par  = (const float*)d_in[9];
    const float* out_w  = (const float*)d_in[10];
    const float* fn_w   = (const float*)d_in[11];

    float* ws = (float*)d_ws;
    // layout (floats); xn and y share a region (disjoint lifetimes within a layer)
    float* x    = ws;                       // TOK*DM
    float* xny  = x    + (size_t)TOK*DM;    // TOK*DI (xn uses first TOK*DM; y uses all)
    float* xz   = xny  + (size_t)TOK*DI;    // TOK*2*DI
    float* xi   = xz   + (size_t)TOK*2*DI;  // TOK*DI
    float* xdbl = xi   + (size_t)TOK*DI;    // TOK*XDBL
    float* dt   = xdbl + (size_t)TOK*XDBL;  // TOK*DI
    float* xn = xny;
    float* y  = xny;

    // x = fuse_feature
    copy_kernel<<<(TOK*DM + 255)/256, 256, 0, stream>>>(x, fuse, TOK*DM);

    for (int i = 0; i < NL; i++) {
        const float* inw  = in_w   + (size_t)i*2*DI*DM;
        const float* cw   = conv_w + (size_t)i*DI*DC;
        const float* cb   = conv_b + (size_t)i*DI;
        const float* xpw  = xp_w   + (size_t)i*XDBL*DI;
        const float* dtw  = dt_w   + (size_t)i*DI*DTR;
        const float* dtb  = dt_b   + (size_t)i*DI;
        const float* alog = A_log  + (size_t)i*DI*DS;
        const float* dp   = D_par  + (size_t)i*DI;
        const float* ow   = out_w  + (size_t)i*DM*DI;
        const float* nw   = norm_w + (size_t)i*DM;

        // xn = rmsnorm(x, nw)
        rmsnorm_kernel<<<TOK, 256, 0, stream>>>(xn, x, nw);
        // xz = xn @ inw^T   (M=8192, N=1032, K=258)
        gemm_nt64<<<dim3((2*DI+63)/64, (TOK+63)/64), 256, 0, stream>>>(
            xn, inw, nullptr, xz, TOK, 2*DI, DM);
        // xi = silu(causal_conv(xz[:, :DI]))
        conv_silu_kernel<<<(TOK*DI + 255)/256, 256, 0, stream>>>(xi, xz, cw, cb);
        // xdbl = xi @ xpw^T  (M=8192, N=49, K=516)
        gemm_nt64<<<dim3((XDBL+63)/64, (TOK+63)/64), 256, 0, stream>>>(
            xi, xpw, nullptr, xdbl, TOK, XDBL, DI);
        // dt = softplus(xdbl[:, :17] @ dtw^T + dtb)
        dt_kernel<<<(TOK*DI + 255)/256, 256, 0, stream>>>(dt, xdbl, dtw, dtb);
        // y = scan(...) * silu(z), with D skip fused
        scan_kernel<<<(Bv*DI)/16, 256, 0, stream>>>(y, dt, xi, xdbl, xz, alog, dp);
        // x = x + y @ ow^T  (M=8192, N=258, K=516)
        gemm_nt64<<<dim3((DM+63)/64, (TOK+63)/64), 256, 0, stream>>>(
            y, ow, x, x, TOK, DM, DI);
    }

    // out = fuse + rmsnorm(x, fn_w)
    final_kernel<<<TOK, 256, 0, stream>>>((float*)d_out, x, fuse, fn_w);
}

// Round 2
// 2170.480 us; speedup vs baseline: 3.5793x; 3.5793x over previous
//
#include <hip/hip_runtime.h>
#include <math.h>

// Problem constants (from reference)
constexpr int Bv  = 4;
constexpr int Lv  = 2048;
constexpr int DM  = 258;            // d_model
constexpr int NL  = 4;              // layers
constexpr int DS  = 16;             // d_state
constexpr int DC  = 4;              // d_conv
constexpr int DI  = 516;            // d_inner
constexpr int DTR = 17;             // dt_rank
constexpr int XDBL = DTR + 2*DS;    // 49
constexpr int TOK = Bv*Lv;          // 8192
constexpr float EPS = 1e-5f;

// chunked scan params
constexpr int CT = 64;              // chunk length
constexpr int NC = Lv / CT;         // 32 chunks per sequence
constexpr int NCC = Bv * NC * DI;   // 66048 channel-chunks (divisible by 256)

// ---------------- rmsnorm: one block (256 thr) per token ----------------
__global__ void rmsnorm_kernel(float* __restrict__ out, const float* __restrict__ x,
                               const float* __restrict__ w) {
    int tok = blockIdx.x;
    const float* xr = x + (size_t)tok*DM;
    int t = threadIdx.x;
    float v0 = xr[t];
    float v1 = (t < DM-256) ? xr[256+t] : 0.f;
    float ss = v0*v0 + v1*v1;
    for (int o = 32; o; o >>= 1) ss += __shfl_down(ss, o, 64);
    __shared__ float red[4];
    int wid = t >> 6, lane = t & 63;
    if (lane == 0) red[wid] = ss;
    __syncthreads();
    float tot = red[0]+red[1]+red[2]+red[3];
    float r = rsqrtf(tot/(float)DM + EPS);
    float* outr = out + (size_t)tok*DM;
    outr[t] = v0*r*w[t];
    if (t < DM-256) outr[256+t] = v1*r*w[256+t];
}

// ---------------- final: out = fuse + rmsnorm(x, w) ----------------
__global__ void final_kernel(float* __restrict__ out, const float* __restrict__ x,
                             const float* __restrict__ fuse, const float* __restrict__ w) {
    int tok = blockIdx.x;
    const float* xr = x + (size_t)tok*DM;
    const float* fr = fuse + (size_t)tok*DM;
    int t = threadIdx.x;
    float v0 = xr[t];
    float v1 = (t < DM-256) ? xr[256+t] : 0.f;
    float ss = v0*v0 + v1*v1;
    for (int o = 32; o; o >>= 1) ss += __shfl_down(ss, o, 64);
    __shared__ float red[4];
    int wid = t >> 6, lane = t & 63;
    if (lane == 0) red[wid] = ss;
    __syncthreads();
    float tot = red[0]+red[1]+red[2]+red[3];
    float r = rsqrtf(tot/(float)DM + EPS);
    float* outr = out + (size_t)tok*DM;
    outr[t] = fr[t] + v0*r*w[t];
    if (t < DM-256) outr[256+t] = fr[256+t] + v1*r*w[256+t];
}

// ---------------- NT GEMM: C[M,N] = A[M,K] * Bw[N,K]^T (+resid) ----------------
// 64x64 tile, BK=16, 256 threads, 4x4 outputs/thread
__global__ __launch_bounds__(256) void gemm_nt64(
    const float* __restrict__ A, const float* __restrict__ Bw,
    const float* __restrict__ resid, float* __restrict__ C,
    int M, int N, int K) {
    __shared__ float As[64][17];
    __shared__ float Bs[64][17];
    int tid = threadIdx.x;
    int tx = tid & 15, ty = tid >> 4;
    int row0 = blockIdx.y * 64, col0 = blockIdx.x * 64;
    float acc[4][4] = {};
    for (int k0 = 0; k0 < K; k0 += 16) {
        for (int i = 0; i < 4; i++) {
            int e = tid + i*256;
            int m = e >> 4, k = e & 15;
            int gk = k0 + k;
            int gm = row0 + m;
            As[m][k] = (gm < M && gk < K) ? A[(size_t)gm*K + gk] : 0.f;
            int gn = col0 + m;
            Bs[m][k] = (gn < N && gk < K) ? Bw[(size_t)gn*K + gk] : 0.f;
        }
        __syncthreads();
        int kmax = (K - k0 < 16) ? (K - k0) : 16;
        for (int kk = 0; kk < kmax; kk++) {
            float a[4], b[4];
            #pragma unroll
            for (int i = 0; i < 4; i++) a[i] = As[ty*4+i][kk];
            #pragma unroll
            for (int j = 0; j < 4; j++) b[j] = Bs[tx*4+j][kk];
            #pragma unroll
            for (int i = 0; i < 4; i++)
                #pragma unroll
                for (int j = 0; j < 4; j++)
                    acc[i][j] += a[i]*b[j];
        }
        __syncthreads();
    }
    for (int i = 0; i < 4; i++) {
        int gm = row0 + ty*4 + i;
        if (gm >= M) continue;
        for (int j = 0; j < 4; j++) {
            int gn = col0 + tx*4 + j;
            if (gn >= N) continue;
            float v = acc[i][j];
            if (resid) v += resid[(size_t)gm*N + gn];
            C[(size_t)gm*N + gn] = v;
        }
    }
}

// ---------------- causal depthwise conv (k=4) + silu ----------------
__global__ void conv_silu_kernel(float* __restrict__ xi, const float* __restrict__ xz,
                                 const float* __restrict__ cw, const float* __restrict__ cb) {
    int idx = blockIdx.x*256 + threadIdx.x;
    if (idx >= TOK*DI) return;
    int d = idx % DI, tok = idx / DI;
    int l = tok % Lv;
    float acc = cb[d];
    #pragma unroll
    for (int j = 0; j < DC; j++) {
        int lj = l - (DC-1) + j;
        if (lj >= 0)
            acc += xz[(size_t)(tok - (DC-1) + j)*(2*DI) + d] * cw[d*DC + j];
    }
    xi[idx] = acc / (1.f + __expf(-acc));   // silu
}

// ---------------- dt = softplus(dt_lo @ dtw^T + dtb) ----------------
__global__ void dt_kernel(float* __restrict__ dt, const float* __restrict__ xdbl,
                          const float* __restrict__ dtw, const float* __restrict__ dtb) {
    int idx = blockIdx.x*256 + threadIdx.x;
    if (idx >= TOK*DI) return;
    int d = idx % DI, tok = idx / DI;
    const float* xr = xdbl + (size_t)tok*XDBL;
    float acc = dtb[d];
    #pragma unroll
    for (int r = 0; r < DTR; r++) acc += xr[r] * dtw[d*DTR + r];
    dt[idx] = fmaxf(acc, 0.f) + log1pf(__expf(-fabsf(acc)));
}

// ================= chunked parallel scan =================
// Pass 1: per (b, chunk, d) thread — local scan from h=0 over CT steps.
// Stores final local h[16] and sum(dt) (since prod exp(dt*a) = exp(a*sum_dt)).
__global__ __launch_bounds__(256) void scan_chunk(
    const float* __restrict__ dt, const float* __restrict__ xi,
    const float* __restrict__ xdbl, const float* __restrict__ A_log,
    float* __restrict__ sumdt_ws, float* __restrict__ H_ws) {
    int g = blockIdx.x*256 + threadIdx.x;   // [0, NCC)
    int d = g % DI;
    int bc = g / DI;                        // b*NC + c
    int b = bc / NC, c = bc % NC;
    float a[DS];
    #pragma unroll
    for (int s = 0; s < DS; s++) a[s] = -__expf(A_log[d*DS + s]);
    float h[DS];
    #pragma unroll
    for (int s = 0; s < DS; s++) h[s] = 0.f;
    float sdt = 0.f;
    size_t tok0 = (size_t)b*Lv + (size_t)c*CT;
    for (int t = 0; t < CT; t++) {
        size_t tok = tok0 + t;
        float dtv = dt[tok*DI + d];
        float u   = xi[tok*DI + d];
        float du  = dtv * u;
        sdt += dtv;
        const float* Bp = xdbl + tok*XDBL + DTR;
        #pragma unroll
        for (int s = 0; s < DS; s++) {
            float g_ = __expf(dtv * a[s]);
            h[s] = g_*h[s] + du*Bp[s];
        }
    }
    sumdt_ws[g] = sdt;
    float* Hp = H_ws + (size_t)g*DS;
    #pragma unroll
    for (int s = 0; s < DS; s++) Hp[s] = h[s];
}

// Pass 2: per (b,d,s) thread — sequential combine over NC chunks.
// hinit[c] = state entering chunk c.
__global__ __launch_bounds__(256) void scan_combine(
    const float* __restrict__ sumdt_ws, const float* __restrict__ H_ws,
    const float* __restrict__ A_log, float* __restrict__ hinit_ws) {
    int g = blockIdx.x*256 + threadIdx.x;   // [0, Bv*DI*DS) = 33024
    int s = g & (DS-1);
    int bd = g >> 4;
    int d = bd % DI, b = bd / DI;
    float a = -__expf(A_log[d*DS + s]);
    float h = 0.f;
    for (int c = 0; c < NC; c++) {
        size_t cc = ((size_t)(b*NC + c))*DI + d;
        hinit_ws[cc*DS + s] = h;
        float sdt = sumdt_ws[cc];
        float Hv  = H_ws[cc*DS + s];
        h = __expf(a*sdt)*h + Hv;
    }
}

// Pass 3: per (b, chunk, d) thread — re-scan chunk from hinit, fused with
// C-projection, D skip, and silu(z) gate. Writes y.
__global__ __launch_bounds__(256) void scan_final(
    const float* __restrict__ dt, const float* __restrict__ xi,
    const float* __restrict__ xdbl, const float* __restrict__ xz,
    const float* __restrict__ A_log, const float* __restrict__ Dp,
    const float* __restrict__ hinit_ws, float* __restrict__ y) {
    int g = blockIdx.x*256 + threadIdx.x;   // [0, NCC)
    int d = g % DI;
    int bc = g / DI;
    int b = bc / NC, c = bc % NC;
    float a[DS];
    #pragma unroll
    for (int s = 0; s < DS; s++) a[s] = -__expf(A_log[d*DS + s]);
    float Dv = Dp[d];
    float h[DS];
    const float* hip_ = hinit_ws + (size_t)g*DS;
    #pragma unroll
    for (int s = 0; s < DS; s++) h[s] = hip_[s];
    size_t tok0 = (size_t)b*Lv + (size_t)c*CT;
    for (int t = 0; t < CT; t++) {
        size_t tok = tok0 + t;
        float dtv = dt[tok*DI + d];
        float u   = xi[tok*DI + d];
        float du  = dtv * u;
        const float* Bp = xdbl + tok*XDBL + DTR;
        const float* Cp = Bp + DS;
        float yv = 0.f;
        #pragma unroll
        for (int s = 0; s < DS; s++) {
            float g_ = __expf(dtv * a[s]);
            h[s] = g_*h[s] + du*Bp[s];
            yv += h[s]*Cp[s];
        }
        yv += u*Dv;
        float zv = xz[tok*(2*DI) + DI + d];
        y[tok*DI + d] = yv * (zv / (1.f + __expf(-zv)));
    }
}

extern "C" void kernel_launch(void* const* d_in, const int* in_sizes, int n_in,
                              void* d_out, int out_size, void* d_ws, size_t ws_size,
                              hipStream_t stream) {
    const float* fuse   = (const float*)d_in[0];
    const float* norm_w = (const float*)d_in[1];
    const float* in_w   = (const float*)d_in[2];
    const float* conv_w = (const float*)d_in[3];
    const float* conv_b = (const float*)d_in[4];
    const float* xp_w   = (const float*)d_in[5];
    const float* dt_w   = (const float*)d_in[6];
    const float* dt_b   = (const float*)d_in[7];
    const float* A_log  = (const float*)d_in[8];
    const float* D_par  = (const float*)d_in[9];
    const float* out_w  = (const float*)d_in[10];
    const float* fn_w   = (const float*)d_in[11];

    float* ws = (float*)d_ws;
    float* x     = ws;                        // TOK*DM
    float* xny   = x     + (size_t)TOK*DM;    // TOK*DI (xn; later y)
    float* xz    = xny   + (size_t)TOK*DI;    // TOK*2*DI
    float* xi    = xz    + (size_t)TOK*2*DI;  // TOK*DI
    float* xdbl  = xi    + (size_t)TOK*DI;    // TOK*XDBL
    float* dt    = xdbl  + (size_t)TOK*XDBL;  // TOK*DI
    float* sumdt = dt    + (size_t)TOK*DI;    // NCC
    float* Hws   = sumdt + (size_t)NCC;       // NCC*DS
    float* hinit = Hws   + (size_t)NCC*DS;    // NCC*DS
    float* xn = xny;
    float* y  = xny;

    for (int i = 0; i < NL; i++) {
        const float* inw  = in_w   + (size_t)i*2*DI*DM;
        const float* cw   = conv_w + (size_t)i*DI*DC;
        const float* cb   = conv_b + (size_t)i*DI;
        const float* xpw  = xp_w   + (size_t)i*XDBL*DI;
        const float* dtw  = dt_w   + (size_t)i*DI*DTR;
        const float* dtb  = dt_b   + (size_t)i*DI;
        const float* alog = A_log  + (size_t)i*DI*DS;
        const float* dp   = D_par  + (size_t)i*DI;
        const float* ow   = out_w  + (size_t)i*DM*DI;
        const float* nw   = norm_w + (size_t)i*DM;
        const float* xcur = (i == 0) ? fuse : x;   // residual input

        // xn = rmsnorm(xcur, nw)
        rmsnorm_kernel<<<TOK, 256, 0, stream>>>(xn, xcur, nw);
        // xz = xn @ inw^T   (M=8192, N=1032, K=258)
        gemm_nt64<<<dim3((2*DI+63)/64, (TOK+63)/64), 256, 0, stream>>>(
            xn, inw, nullptr, xz, TOK, 2*DI, DM);
        // xi = silu(causal_conv(xz[:, :DI]))
        conv_silu_kernel<<<(TOK*DI + 255)/256, 256, 0, stream>>>(xi, xz, cw, cb);
        // xdbl = xi @ xpw^T  (M=8192, N=49, K=516)
        gemm_nt64<<<dim3((XDBL+63)/64, (TOK+63)/64), 256, 0, stream>>>(
            xi, xpw, nullptr, xdbl, TOK, XDBL, DI);
        // dt = softplus(xdbl[:, :17] @ dtw^T + dtb)
        dt_kernel<<<(TOK*DI + 255)/256, 256, 0, stream>>>(dt, xdbl, dtw, dtb);
        // chunked parallel scan
        scan_chunk<<<NCC/256, 256, 0, stream>>>(dt, xi, xdbl, alog, sumdt, Hws);
        scan_combine<<<(Bv*DI*DS)/256, 256, 0, stream>>>(sumdt, Hws, alog, hinit);
        scan_final<<<NCC/256, 256, 0, stream>>>(dt, xi, xdbl, xz, alog, dp, hinit, y);
        // x = xcur + y @ ow^T  (M=8192, N=258, K=516)
        gemm_nt64<<<dim3((DM+63)/64, (TOK+63)/64), 256, 0, stream>>>(
            y, ow, xcur, x, TOK, DM, DI);
    }

    // out = fuse + rmsnorm(x, fn_w)
    final_kernel<<<TOK, 256, 0, stream>>>((float*)d_out, x, fuse, fn_w);
}

// Round 3
// 1143.851 us; speedup vs baseline: 6.7919x; 1.8975x over previous
//
#include <hip/hip_runtime.h>
#include <hip/hip_bf16.h>
#include <math.h>

// Problem constants
constexpr int Bv  = 4;
constexpr int Lv  = 2048;
constexpr int DM  = 258;            // d_model
constexpr int NL  = 4;              // layers
constexpr int DS  = 16;             // d_state
constexpr int DC  = 4;              // d_conv
constexpr int DI  = 516;            // d_inner
constexpr int DTR = 17;             // dt_rank
constexpr int TOK = Bv*Lv;          // 8192
constexpr float EPS = 1e-5f;

// padded dims (tile-multiple so MFMA GEMM needs no bounds checks in the loop)
constexpr int DMp = 288;    // in_proj K pad; x / xn row stride
constexpr int N1p = 1152;   // in_proj N pad (1032->1152 = 9*128); xz row stride
constexpr int DIp = 544;    // x/out_proj K pad; xi_b / y row stride
constexpr int XDp = 128;    // x_proj N pad (49->128); xdbl row stride
constexpr int N3p = 384;    // out_proj N pad (258->384)

// chunked scan params
constexpr int CT = 64;
constexpr int NC = Lv / CT;         // 32
constexpr int NCC = Bv * NC * DI;   // 66048

typedef __bf16 bf16x8 __attribute__((ext_vector_type(8)));
typedef float  floatx4 __attribute__((ext_vector_type(4)));

#if defined(__has_builtin)
#if __has_builtin(__builtin_amdgcn_global_load_lds)
#define USE_ASYNC_LDS 1
#endif
#endif

// ---------------- weight convert + pad: f32 [L][N][K] -> bf16 [L][Np][Kp] ----------------
__global__ void cvt_pad_kernel(__hip_bfloat16* __restrict__ dst, const float* __restrict__ src,
                               int N, int K, int Np, int Kp, int total) {
    int idx = blockIdx.x*256 + threadIdx.x;
    if (idx >= total) return;
    int k = idx % Kp; int t = idx / Kp; int n = t % Np; int l = t / Np;
    float v = (n < N && k < K) ? src[((size_t)l*N + n)*K + k] : 0.f;
    dst[idx] = __float2bfloat16(v);
}

// ---------------- zero bf16 pad columns of xi_b and y ----------------
__global__ void zero_pads_kernel(__hip_bfloat16* __restrict__ xi_b, __hip_bfloat16* __restrict__ y) {
    constexpr int PAD = DIp - DI;   // 28
    int idx = blockIdx.x*256 + threadIdx.x;
    if (idx >= 2*TOK*PAD) return;
    int c = idx % PAD; int t = idx / PAD; int row = t % TOK; int sel = t / TOK;
    __hip_bfloat16* buf = sel ? y : xi_b;
    buf[(size_t)row*DIp + DI + c] = __float2bfloat16(0.f);
}

// ---------------- rmsnorm -> bf16 padded [TOK][DMp] ----------------
__global__ void rmsnorm_kernel(__hip_bfloat16* __restrict__ out, const float* __restrict__ x,
                               int ldx, const float* __restrict__ w) {
    int tok = blockIdx.x;
    const float* xr = x + (size_t)tok*ldx;
    int t = threadIdx.x;
    float v0 = xr[t];
    float v1 = (t < DM-256) ? xr[256+t] : 0.f;
    float ss = v0*v0 + v1*v1;
    for (int o = 32; o; o >>= 1) ss += __shfl_down(ss, o, 64);
    __shared__ float red[4];
    int wid = t >> 6, lane = t & 63;
    if (lane == 0) red[wid] = ss;
    __syncthreads();
    float tot = red[0]+red[1]+red[2]+red[3];
    float r = rsqrtf(tot/(float)DM + EPS);
    __hip_bfloat16* outr = out + (size_t)tok*DMp;
    outr[t] = __float2bfloat16(v0*r*w[t]);
    if (t < DM-256) outr[256+t] = __float2bfloat16(v1*r*w[256+t]);
    else if (t < DMp-256) outr[256+t] = __float2bfloat16(0.f);   // pad cols 258..287
}

// ---------------- final: out = fuse + rmsnorm(x, w) ----------------
__global__ void final_kernel(float* __restrict__ out, const float* __restrict__ x,
                             const float* __restrict__ fuse, const float* __restrict__ w) {
    int tok = blockIdx.x;
    const float* xr = x + (size_t)tok*DMp;
    const float* fr = fuse + (size_t)tok*DM;
    int t = threadIdx.x;
    float v0 = xr[t];
    float v1 = (t < DM-256) ? xr[256+t] : 0.f;
    float ss = v0*v0 + v1*v1;
    for (int o = 32; o; o >>= 1) ss += __shfl_down(ss, o, 64);
    __shared__ float red[4];
    int wid = t >> 6, lane = t & 63;
    if (lane == 0) red[wid] = ss;
    __syncthreads();
    float tot = red[0]+red[1]+red[2]+red[3];
    float r = rsqrtf(tot/(float)DM + EPS);
    float* outr = out + (size_t)tok*DM;
    outr[t] = fr[t] + v0*r*w[t];
    if (t < DM-256) outr[256+t] = fr[256+t] + v1*r*w[256+t];
}

// ---------------- bf16 MFMA NT-GEMM: C[M][N] = A[M][K] * B[N][K]^T (+resid) ----------------
// 128x128 tile, BK=32, 256 threads (4 waves), wave quadrant 64x64 = 4x4 mfma 16x16x32.
// All loads unguarded (buffers padded); store guarded by nstore.
__global__ __launch_bounds__(256) void gemm_bf16(
    const __hip_bfloat16* __restrict__ A, int lda,
    const __hip_bfloat16* __restrict__ B, int ldb,
    float* __restrict__ C, int ldc, int nstore,
    const float* __restrict__ resid, int ldr, int K) {
    __shared__ unsigned short Asm[128*32];
    __shared__ unsigned short Bsm[128*32];
    int tid = threadIdx.x;
    int w = tid >> 6, lane = tid & 63;
    int row0 = blockIdx.y * 128, col0 = blockIdx.x * 128;

    // staging coords: wave w stages rows [w*32, w*32+32) of A and B tiles
    int srow = lane >> 2;          // 0..15
    int scol = (lane & 3) * 8;     // 0,8,16,24

    const __hip_bfloat16* Ag = A + (size_t)(row0 + w*32 + srow)*lda + scol;
    const __hip_bfloat16* Bg = B + (size_t)(col0 + w*32 + srow)*ldb + scol;

    // MFMA fragment coords: wave quadrant
    int wr = (w >> 1) * 64, wc = (w & 1) * 64;
    int fr_row = lane & 15;
    int fr_k   = (lane >> 4) * 8;

    floatx4 acc[4][4];
    #pragma unroll
    for (int i = 0; i < 4; i++)
        #pragma unroll
        for (int j = 0; j < 4; j++)
            acc[i][j] = (floatx4){0.f, 0.f, 0.f, 0.f};

    for (int k0 = 0; k0 < K; k0 += 32) {
#ifdef USE_ASYNC_LDS
        __builtin_amdgcn_global_load_lds(
            (const __attribute__((address_space(1))) unsigned int*)Ag,
            (__attribute__((address_space(3))) unsigned int*)&Asm[(w*32)*32], 16, 0, 0);
        __builtin_amdgcn_global_load_lds(
            (const __attribute__((address_space(1))) unsigned int*)(Ag + 16*lda),
            (__attribute__((address_space(3))) unsigned int*)&Asm[(w*32+16)*32], 16, 0, 0);
        __builtin_amdgcn_global_load_lds(
            (const __attribute__((address_space(1))) unsigned int*)Bg,
            (__attribute__((address_space(3))) unsigned int*)&Bsm[(w*32)*32], 16, 0, 0);
        __builtin_amdgcn_global_load_lds(
            (const __attribute__((address_space(1))) unsigned int*)(Bg + 16*ldb),
            (__attribute__((address_space(3))) unsigned int*)&Bsm[(w*32+16)*32], 16, 0, 0);
#else
        {
            int4 va0 = *(const int4*)Ag;
            int4 va1 = *(const int4*)(Ag + 16*lda);
            int4 vb0 = *(const int4*)Bg;
            int4 vb1 = *(const int4*)(Bg + 16*ldb);
            *(int4*)&Asm[(w*32 + srow)*32 + scol]      = va0;
            *(int4*)&Asm[(w*32 + 16 + srow)*32 + scol] = va1;
            *(int4*)&Bsm[(w*32 + srow)*32 + scol]      = vb0;
            *(int4*)&Bsm[(w*32 + 16 + srow)*32 + scol] = vb1;
        }
#endif
        Ag += 32; Bg += 32;
        __syncthreads();

        bf16x8 af[4], bfr[4];
        #pragma unroll
        for (int rb = 0; rb < 4; rb++)
            af[rb] = *(const bf16x8*)&Asm[(wr + rb*16 + fr_row)*32 + fr_k];
        #pragma unroll
        for (int cb = 0; cb < 4; cb++)
            bfr[cb] = *(const bf16x8*)&Bsm[(wc + cb*16 + fr_row)*32 + fr_k];
        #pragma unroll
        for (int rb = 0; rb < 4; rb++)
            #pragma unroll
            for (int cb = 0; cb < 4; cb++)
                acc[rb][cb] = __builtin_amdgcn_mfma_f32_16x16x32_bf16(
                    af[rb], bfr[cb], acc[rb][cb], 0, 0, 0);
        __syncthreads();
    }

    // epilogue: C/D layout col=lane&15, row=(lane>>4)*4+reg
    #pragma unroll
    for (int rb = 0; rb < 4; rb++) {
        int gm0 = row0 + wr + rb*16 + (lane >> 4)*4;
        #pragma unroll
        for (int cb = 0; cb < 4; cb++) {
            int gn = col0 + wc + cb*16 + (lane & 15);
            if (gn < nstore) {
                #pragma unroll
                for (int r = 0; r < 4; r++) {
                    float v = acc[rb][cb][r];
                    if (resid) v += resid[(size_t)(gm0 + r)*ldr + gn];
                    C[(size_t)(gm0 + r)*ldc + gn] = v;
                }
            }
        }
    }
}

// ---------------- causal depthwise conv (k=4) + silu; writes f32 (for scan) + bf16 (for GEMM) ----------------
__global__ void conv_silu_kernel(float* __restrict__ xi_f, __hip_bfloat16* __restrict__ xi_b,
                                 const float* __restrict__ xz,
                                 const float* __restrict__ cw, const float* __restrict__ cb) {
    int idx = blockIdx.x*256 + threadIdx.x;
    if (idx >= TOK*DI) return;
    int d = idx % DI, tok = idx / DI;
    int l = tok % Lv;
    float acc = cb[d];
    #pragma unroll
    for (int j = 0; j < DC; j++) {
        int lj = l - (DC-1) + j;
        if (lj >= 0)
            acc += xz[(size_t)(tok - (DC-1) + j)*N1p + d] * cw[d*DC + j];
    }
    float s = acc / (1.f + __expf(-acc));
    xi_f[(size_t)tok*DI + d] = s;
    xi_b[(size_t)tok*DIp + d] = __float2bfloat16(s);
}

// ---------------- dt = softplus(xdbl[:, :17] @ dtw^T + dtb) ----------------
__global__ void dt_kernel(float* __restrict__ dt, const float* __restrict__ xdbl,
                          const float* __restrict__ dtw, const float* __restrict__ dtb) {
    int idx = blockIdx.x*256 + threadIdx.x;
    if (idx >= TOK*DI) return;
    int d = idx % DI, tok = idx / DI;
    const float* xr = xdbl + (size_t)tok*XDp;
    float acc = dtb[d];
    #pragma unroll
    for (int r = 0; r < DTR; r++) acc += xr[r] * dtw[d*DTR + r];
    dt[idx] = fmaxf(acc, 0.f) + log1pf(__expf(-fabsf(acc)));
}

// ================= chunked parallel scan =================
__global__ __launch_bounds__(256) void scan_chunk(
    const float* __restrict__ dt, const float* __restrict__ xi,
    const float* __restrict__ xdbl, const float* __restrict__ A_log,
    float* __restrict__ sumdt_ws, float* __restrict__ H_ws) {
    int g = blockIdx.x*256 + threadIdx.x;
    int d = g % DI;
    int bc = g / DI;
    int b = bc / NC, c = bc % NC;
    float a[DS];
    #pragma unroll
    for (int s = 0; s < DS; s++) a[s] = -__expf(A_log[d*DS + s]);
    float h[DS];
    #pragma unroll
    for (int s = 0; s < DS; s++) h[s] = 0.f;
    float sdt = 0.f;
    size_t tok0 = (size_t)b*Lv + (size_t)c*CT;
    for (int t = 0; t < CT; t++) {
        size_t tok = tok0 + t;
        float dtv = dt[tok*DI + d];
        float u   = xi[tok*DI + d];
        float du  = dtv * u;
        sdt += dtv;
        const float* Bp = xdbl + tok*XDp + DTR;
        #pragma unroll
        for (int s = 0; s < DS; s++) {
            float g_ = __expf(dtv * a[s]);
            h[s] = g_*h[s] + du*Bp[s];
        }
    }
    sumdt_ws[g] = sdt;
    float* Hp = H_ws + (size_t)g*DS;
    #pragma unroll
    for (int s = 0; s < DS; s++) Hp[s] = h[s];
}

__global__ __launch_bounds__(256) void scan_combine(
    const float* __restrict__ sumdt_ws, const float* __restrict__ H_ws,
    const float* __restrict__ A_log, float* __restrict__ hinit_ws) {
    int g = blockIdx.x*256 + threadIdx.x;   // [0, Bv*DI*DS)
    int s = g & (DS-1);
    int bd = g >> 4;
    int d = bd % DI, b = bd / DI;
    float a = -__expf(A_log[d*DS + s]);
    float h = 0.f;
    for (int c = 0; c < NC; c++) {
        size_t cc = ((size_t)(b*NC + c))*DI + d;
        hinit_ws[cc*DS + s] = h;
        float sdt = sumdt_ws[cc];
        float Hv  = H_ws[cc*DS + s];
        h = __expf(a*sdt)*h + Hv;
    }
}

__global__ __launch_bounds__(256) void scan_final(
    const float* __restrict__ dt, const float* __restrict__ xi,
    const float* __restrict__ xdbl, const float* __restrict__ xz,
    const float* __restrict__ A_log, const float* __restrict__ Dp,
    const float* __restrict__ hinit_ws, __hip_bfloat16* __restrict__ y) {
    int g = blockIdx.x*256 + threadIdx.x;
    int d = g % DI;
    int bc = g / DI;
    int b = bc / NC, c = bc % NC;
    float a[DS];
    #pragma unroll
    for (int s = 0; s < DS; s++) a[s] = -__expf(A_log[d*DS + s]);
    float Dv = Dp[d];
    float h[DS];
    const float* hp = hinit_ws + (size_t)g*DS;
    #pragma unroll
    for (int s = 0; s < DS; s++) h[s] = hp[s];
    size_t tok0 = (size_t)b*Lv + (size_t)c*CT;
    for (int t = 0; t < CT; t++) {
        size_t tok = tok0 + t;
        float dtv = dt[tok*DI + d];
        float u   = xi[tok*DI + d];
        float du  = dtv * u;
        const float* Bp = xdbl + tok*XDp + DTR;
        const float* Cp = Bp + DS;
        float yv = 0.f;
        #pragma unroll
        for (int s = 0; s < DS; s++) {
            float g_ = __expf(dtv * a[s]);
            h[s] = g_*h[s] + du*Bp[s];
            yv += h[s]*Cp[s];
        }
        yv += u*Dv;
        float zv = xz[tok*N1p + DI + d];
        y[tok*DIp + d] = __float2bfloat16(yv * (zv / (1.f + __expf(-zv))));
    }
}

extern "C" void kernel_launch(void* const* d_in, const int* in_sizes, int n_in,
                              void* d_out, int out_size, void* d_ws, size_t ws_size,
                              hipStream_t stream) {
    const float* fuse   = (const float*)d_in[0];
    const float* norm_w = (const float*)d_in[1];
    const float* in_w   = (const float*)d_in[2];
    const float* conv_w = (const float*)d_in[3];
    const float* conv_b = (const float*)d_in[4];
    const float* xp_w   = (const float*)d_in[5];
    const float* dt_w   = (const float*)d_in[6];
    const float* dt_b   = (const float*)d_in[7];
    const float* A_log  = (const float*)d_in[8];
    const float* D_par  = (const float*)d_in[9];
    const float* out_w  = (const float*)d_in[10];
    const float* fn_w   = (const float*)d_in[11];

    char* p = (char*)d_ws;
    auto alloc = [&](size_t bytes) { char* r = p; p += (bytes + 255) & ~(size_t)255; return r; };

    float*          x     = (float*)         alloc((size_t)TOK*DMp*4);
    __hip_bfloat16* xn    = (__hip_bfloat16*)alloc((size_t)TOK*DMp*2);
    float*          xz    = (float*)         alloc((size_t)TOK*N1p*4);
    float*          xi_f  = (float*)         alloc((size_t)TOK*DI*4);
    __hip_bfloat16* xi_b  = (__hip_bfloat16*)alloc((size_t)TOK*DIp*2);
    float*          xdbl  = (float*)         alloc((size_t)TOK*XDp*4);
    float*          dt    = (float*)         alloc((size_t)TOK*DI*4);
    __hip_bfloat16* y     = (__hip_bfloat16*)alloc((size_t)TOK*DIp*2);
    float*          sumdt = (float*)         alloc((size_t)NCC*4);
    float*          Hws   = (float*)         alloc((size_t)NCC*DS*4);
    float*          hinit = (float*)         alloc((size_t)NCC*DS*4);
    __hip_bfloat16* W1b   = (__hip_bfloat16*)alloc((size_t)NL*N1p*DMp*2);
    __hip_bfloat16* W2b   = (__hip_bfloat16*)alloc((size_t)NL*XDp*DIp*2);
    __hip_bfloat16* W3b   = (__hip_bfloat16*)alloc((size_t)NL*N3p*DIp*2);

    // weight conversion (all layers at once)
    {
        int t1 = NL*N1p*DMp, t2 = NL*XDp*DIp, t3 = NL*N3p*DIp;
        cvt_pad_kernel<<<(t1+255)/256, 256, 0, stream>>>(W1b, in_w, 2*DI, DM, N1p, DMp, t1);
        cvt_pad_kernel<<<(t2+255)/256, 256, 0, stream>>>(W2b, xp_w, DTR+2*DS, DI, XDp, DIp, t2);
        cvt_pad_kernel<<<(t3+255)/256, 256, 0, stream>>>(W3b, out_w, DM, DI, N3p, DIp, t3);
        int tz = 2*TOK*(DIp-DI);
        zero_pads_kernel<<<(tz+255)/256, 256, 0, stream>>>(xi_b, y);
    }

    for (int i = 0; i < NL; i++) {
        const __hip_bfloat16* w1 = W1b + (size_t)i*N1p*DMp;
        const __hip_bfloat16* w2 = W2b + (size_t)i*XDp*DIp;
        const __hip_bfloat16* w3 = W3b + (size_t)i*N3p*DIp;
        const float* cw   = conv_w + (size_t)i*DI*DC;
        const float* cb   = conv_b + (size_t)i*DI;
        const float* dtw  = dt_w   + (size_t)i*DI*DTR;
        const float* dtb  = dt_b   + (size_t)i*DI;
        const float* alog = A_log  + (size_t)i*DI*DS;
        const float* dp   = D_par  + (size_t)i*DI;
        const float* nw   = norm_w + (size_t)i*DM;
        const float* xcur = (i == 0) ? fuse : x;
        int ld_cur = (i == 0) ? DM : DMp;

        // xn = bf16(rmsnorm(xcur))
        rmsnorm_kernel<<<TOK, 256, 0, stream>>>(xn, xcur, ld_cur, nw);
        // xz = xn @ W1^T   (M=8192, N=1152(1032), K=288)
        gemm_bf16<<<dim3(N1p/128, TOK/128), 256, 0, stream>>>(
            xn, DMp, w1, DMp, xz, N1p, N1p, nullptr, 0, DMp);
        // xi = silu(causal_conv(xz[:, :DI]))
        conv_silu_kernel<<<(TOK*DI + 255)/256, 256, 0, stream>>>(xi_f, xi_b, xz, cw, cb);
        // xdbl = xi @ W2^T  (M=8192, N=128(49), K=544)
        gemm_bf16<<<dim3(XDp/128, TOK/128), 256, 0, stream>>>(
            xi_b, DIp, w2, DIp, xdbl, XDp, XDp, nullptr, 0, DIp);
        // dt = softplus(xdbl[:, :17] @ dtw^T + dtb)
        dt_kernel<<<(TOK*DI + 255)/256, 256, 0, stream>>>(dt, xdbl, dtw, dtb);
        // chunked parallel scan
        scan_chunk<<<NCC/256, 256, 0, stream>>>(dt, xi_f, xdbl, alog, sumdt, Hws);
        scan_combine<<<(Bv*DI*DS)/256, 256, 0, stream>>>(sumdt, Hws, alog, hinit);
        scan_final<<<NCC/256, 256, 0, stream>>>(dt, xi_f, xdbl, xz, alog, dp, hinit, y);
        // x = xcur + y @ W3^T  (M=8192, N=384(258), K=544)
        gemm_bf16<<<dim3(N3p/128, TOK/128), 256, 0, stream>>>(
            y, DIp, w3, DIp, x, DMp, DM, xcur, ld_cur, DIp);
    }

    // out = fuse + rmsnorm(x, fn_w)
    final_kernel<<<TOK, 256, 0, stream>>>((float*)d_out, x, fuse, fn_w);
}

// Round 4
// 946.728 us; speedup vs baseline: 8.2060x; 1.2082x over previous
//
#include <hip/hip_runtime.h>
#include <hip/hip_bf16.h>
#include <math.h>

// Problem constants
constexpr int Bv  = 4;
constexpr int Lv  = 2048;
constexpr int DM  = 258;            // d_model
constexpr int NL  = 4;              // layers
constexpr int DS  = 16;             // d_state
constexpr int DC  = 4;              // d_conv
constexpr int DI  = 516;            // d_inner
constexpr int DTR = 17;             // dt_rank
constexpr int TOK = Bv*Lv;          // 8192
constexpr float EPS = 1e-5f;

// padded dims (tile-multiple so MFMA GEMM needs no bounds checks in the loop)
constexpr int DMp = 288;    // in_proj K pad; x / xn row stride
constexpr int N1p = 1152;   // in_proj N pad (1032->1152 = 9*128); xz row stride
constexpr int DIp = 544;    // x/out_proj K pad; xi_b / y row stride
constexpr int XDp = 128;    // x_proj N pad (49->128); xdbl row stride
constexpr int N3p = 384;    // out_proj N pad (258->384)

// chunked scan params
constexpr int CT  = 32;             // chunk length
constexpr int NC  = Lv / CT;        // 64 chunks per sequence
constexpr int NCB = Bv * NC;        // 256 (b,chunk) pairs
constexpr int NCD = NCB * DI;       // 132096 channel-chunks

// LDS row layout for staged xdbl rows: [0..16]=dt_lo, [20..35]=B, [36..51]=C
constexpr int LROW = 52;            // 208 B, 16B-aligned stride

typedef __bf16 bf16x8 __attribute__((ext_vector_type(8)));
typedef float  floatx4 __attribute__((ext_vector_type(4)));

#if defined(__has_builtin)
#if __has_builtin(__builtin_amdgcn_global_load_lds)
#define USE_ASYNC_LDS 1
#endif
#endif

// ---------------- weight convert + pad: f32 [L][N][K] -> bf16 [L][Np][Kp] ----------------
__global__ void cvt_pad_kernel(__hip_bfloat16* __restrict__ dst, const float* __restrict__ src,
                               int N, int K, int Np, int Kp, int total) {
    int idx = blockIdx.x*256 + threadIdx.x;
    if (idx >= total) return;
    int k = idx % Kp; int t = idx / Kp; int n = t % Np; int l = t / Np;
    float v = (n < N && k < K) ? src[((size_t)l*N + n)*K + k] : 0.f;
    dst[idx] = __float2bfloat16(v);
}

// ---------------- zero bf16 pad columns of xi_b and y ----------------
__global__ void zero_pads_kernel(__hip_bfloat16* __restrict__ xi_b, __hip_bfloat16* __restrict__ y) {
    constexpr int PAD = DIp - DI;   // 28
    int idx = blockIdx.x*256 + threadIdx.x;
    if (idx >= 2*TOK*PAD) return;
    int c = idx % PAD; int t = idx / PAD; int row = t % TOK; int sel = t / TOK;
    __hip_bfloat16* buf = sel ? y : xi_b;
    buf[(size_t)row*DIp + DI + c] = __float2bfloat16(0.f);
}

// ---------------- rmsnorm -> bf16 padded [TOK][DMp] ----------------
__global__ void rmsnorm_kernel(__hip_bfloat16* __restrict__ out, const float* __restrict__ x,
                               int ldx, const float* __restrict__ w) {
    int tok = blockIdx.x;
    const float* xr = x + (size_t)tok*ldx;
    int t = threadIdx.x;
    float v0 = xr[t];
    float v1 = (t < DM-256) ? xr[256+t] : 0.f;
    float ss = v0*v0 + v1*v1;
    for (int o = 32; o; o >>= 1) ss += __shfl_down(ss, o, 64);
    __shared__ float red[4];
    int wid = t >> 6, lane = t & 63;
    if (lane == 0) red[wid] = ss;
    __syncthreads();
    float tot = red[0]+red[1]+red[2]+red[3];
    float r = rsqrtf(tot/(float)DM + EPS);
    __hip_bfloat16* outr = out + (size_t)tok*DMp;
    outr[t] = __float2bfloat16(v0*r*w[t]);
    if (t < DM-256) outr[256+t] = __float2bfloat16(v1*r*w[256+t]);
    else if (t < DMp-256) outr[256+t] = __float2bfloat16(0.f);   // pad cols 258..287
}

// ---------------- final: out = fuse + rmsnorm(x, w) ----------------
__global__ void final_kernel(float* __restrict__ out, const float* __restrict__ x,
                             const float* __restrict__ fuse, const float* __restrict__ w) {
    int tok = blockIdx.x;
    const float* xr = x + (size_t)tok*DMp;
    const float* fr = fuse + (size_t)tok*DM;
    int t = threadIdx.x;
    float v0 = xr[t];
    float v1 = (t < DM-256) ? xr[256+t] : 0.f;
    float ss = v0*v0 + v1*v1;
    for (int o = 32; o; o >>= 1) ss += __shfl_down(ss, o, 64);
    __shared__ float red[4];
    int wid = t >> 6, lane = t & 63;
    if (lane == 0) red[wid] = ss;
    __syncthreads();
    float tot = red[0]+red[1]+red[2]+red[3];
    float r = rsqrtf(tot/(float)DM + EPS);
    float* outr = out + (size_t)tok*DM;
    outr[t] = fr[t] + v0*r*w[t];
    if (t < DM-256) outr[256+t] = fr[256+t] + v1*r*w[256+t];
}

// ---------------- bf16 MFMA NT-GEMM: C[M][N] = A[M][K] * B[N][K]^T (+resid) ----------------
__global__ __launch_bounds__(256) void gemm_bf16(
    const __hip_bfloat16* __restrict__ A, int lda,
    const __hip_bfloat16* __restrict__ B, int ldb,
    float* __restrict__ C, int ldc, int nstore,
    const float* __restrict__ resid, int ldr, int K) {
    __shared__ unsigned short Asm[128*32];
    __shared__ unsigned short Bsm[128*32];
    int tid = threadIdx.x;
    int w = tid >> 6, lane = tid & 63;
    int row0 = blockIdx.y * 128, col0 = blockIdx.x * 128;

    int srow = lane >> 2;          // 0..15
    int scol = (lane & 3) * 8;     // 0,8,16,24

    const __hip_bfloat16* Ag = A + (size_t)(row0 + w*32 + srow)*lda + scol;
    const __hip_bfloat16* Bg = B + (size_t)(col0 + w*32 + srow)*ldb + scol;

    int wr = (w >> 1) * 64, wc = (w & 1) * 64;
    int fr_row = lane & 15;
    int fr_k   = (lane >> 4) * 8;

    floatx4 acc[4][4];
    #pragma unroll
    for (int i = 0; i < 4; i++)
        #pragma unroll
        for (int j = 0; j < 4; j++)
            acc[i][j] = (floatx4){0.f, 0.f, 0.f, 0.f};

    for (int k0 = 0; k0 < K; k0 += 32) {
#ifdef USE_ASYNC_LDS
        __builtin_amdgcn_global_load_lds(
            (const __attribute__((address_space(1))) unsigned int*)Ag,
            (__attribute__((address_space(3))) unsigned int*)&Asm[(w*32)*32], 16, 0, 0);
        __builtin_amdgcn_global_load_lds(
            (const __attribute__((address_space(1))) unsigned int*)(Ag + 16*lda),
            (__attribute__((address_space(3))) unsigned int*)&Asm[(w*32+16)*32], 16, 0, 0);
        __builtin_amdgcn_global_load_lds(
            (const __attribute__((address_space(1))) unsigned int*)Bg,
            (__attribute__((address_space(3))) unsigned int*)&Bsm[(w*32)*32], 16, 0, 0);
        __builtin_amdgcn_global_load_lds(
            (const __attribute__((address_space(1))) unsigned int*)(Bg + 16*ldb),
            (__attribute__((address_space(3))) unsigned int*)&Bsm[(w*32+16)*32], 16, 0, 0);
#else
        {
            int4 va0 = *(const int4*)Ag;
            int4 va1 = *(const int4*)(Ag + 16*lda);
            int4 vb0 = *(const int4*)Bg;
            int4 vb1 = *(const int4*)(Bg + 16*ldb);
            *(int4*)&Asm[(w*32 + srow)*32 + scol]      = va0;
            *(int4*)&Asm[(w*32 + 16 + srow)*32 + scol] = va1;
            *(int4*)&Bsm[(w*32 + srow)*32 + scol]      = vb0;
            *(int4*)&Bsm[(w*32 + 16 + srow)*32 + scol] = vb1;
        }
#endif
        Ag += 32; Bg += 32;
        __syncthreads();

        bf16x8 af[4], bfr[4];
        #pragma unroll
        for (int rb = 0; rb < 4; rb++)
            af[rb] = *(const bf16x8*)&Asm[(wr + rb*16 + fr_row)*32 + fr_k];
        #pragma unroll
        for (int cb = 0; cb < 4; cb++)
            bfr[cb] = *(const bf16x8*)&Bsm[(wc + cb*16 + fr_row)*32 + fr_k];
        #pragma unroll
        for (int rb = 0; rb < 4; rb++)
            #pragma unroll
            for (int cb = 0; cb < 4; cb++)
                acc[rb][cb] = __builtin_amdgcn_mfma_f32_16x16x32_bf16(
                    af[rb], bfr[cb], acc[rb][cb], 0, 0, 0);
        __syncthreads();
    }

    #pragma unroll
    for (int rb = 0; rb < 4; rb++) {
        int gm0 = row0 + wr + rb*16 + (lane >> 4)*4;
        #pragma unroll
        for (int cb = 0; cb < 4; cb++) {
            int gn = col0 + wc + cb*16 + (lane & 15);
            if (gn < nstore) {
                #pragma unroll
                for (int r = 0; r < 4; r++) {
                    float v = acc[rb][cb][r];
                    if (resid) v += resid[(size_t)(gm0 + r)*ldr + gn];
                    C[(size_t)(gm0 + r)*ldc + gn] = v;
                }
            }
        }
    }
}

// ---------------- causal depthwise conv (k=4) + silu; writes f32 (scan) + bf16 (GEMM) ----------------
__global__ void conv_silu_kernel(float* __restrict__ xi_f, __hip_bfloat16* __restrict__ xi_b,
                                 const float* __restrict__ xz,
                                 const float* __restrict__ cw, const float* __restrict__ cb) {
    int idx = blockIdx.x*256 + threadIdx.x;
    if (idx >= TOK*DI) return;
    int d = idx % DI, tok = idx / DI;
    int l = tok % Lv;
    float acc = cb[d];
    #pragma unroll
    for (int j = 0; j < DC; j++) {
        int lj = l - (DC-1) + j;
        if (lj >= 0)
            acc += xz[(size_t)(tok - (DC-1) + j)*N1p + d] * cw[d*DC + j];
    }
    float s = acc / (1.f + __expf(-acc));
    xi_f[(size_t)tok*DI + d] = s;
    xi_b[(size_t)tok*DIp + d] = __float2bfloat16(s);
}

// ================= chunked parallel scan (block per (b,chunk), LDS-staged xdbl) =================
// dt computed inline: dt = softplus(dt_lo . dtw[d] + dtb[d]); dt_lo shared via LDS.
__device__ __forceinline__ void stage_xdbl(float* xb, const float* __restrict__ xdbl,
                                           size_t tok0, int tid) {
    for (int idx = tid; idx < CT*(DTR+2*DS); idx += 256) {
        int t = idx / 49, c2 = idx % 49;
        int dst = c2 + (c2 >= DTR ? 3 : 0);     // B at 20, C at 36 (16B aligned)
        xb[t*LROW + dst] = xdbl[(tok0 + t)*XDp + c2];
    }
}

__global__ __launch_bounds__(256) void scan_chunk2(
    const float* __restrict__ xi, const float* __restrict__ xdbl,
    const float* __restrict__ A_log, const float* __restrict__ dtw,
    const float* __restrict__ dtb,
    float* __restrict__ sumdt_ws, float* __restrict__ H_ws) {
    __shared__ __attribute__((aligned(16))) float xb[CT*LROW];
    int tid = threadIdx.x;
    int bc = blockIdx.y;                 // 0..NCB-1
    int b = bc / NC, c = bc % NC;
    size_t tok0 = (size_t)b*Lv + (size_t)c*CT;
    stage_xdbl(xb, xdbl, tok0, tid);
    __syncthreads();
    int d = blockIdx.x*256 + tid;        // 0..767
    if (d >= DI) return;

    float a[DS];
    const float* ap = A_log + (size_t)d*DS;
    #pragma unroll
    for (int s = 0; s < DS; s++) a[s] = -__expf(ap[s]);
    float w17[DTR];
    #pragma unroll
    for (int r = 0; r < DTR; r++) w17[r] = dtw[d*DTR + r];
    float dtbv = dtb[d];

    float h[DS];
    #pragma unroll
    for (int s = 0; s < DS; s++) h[s] = 0.f;
    float sdt = 0.f;
    #pragma unroll 2
    for (int t = 0; t < CT; t++) {
        const float* row = xb + t*LROW;
        float u = xi[(tok0 + t)*DI + d];
        float acc = dtbv;
        #pragma unroll
        for (int r = 0; r < DTR; r++) acc = fmaf(row[r], w17[r], acc);
        float dtv = fmaxf(acc, 0.f) + log1pf(__expf(-fabsf(acc)));
        float du = dtv * u;
        sdt += dtv;
        #pragma unroll
        for (int s = 0; s < DS; s++)
            h[s] = __expf(dtv*a[s])*h[s] + du*row[20+s];
    }
    size_t cc = (size_t)bc*DI + d;
    sumdt_ws[cc] = sdt;
    float* Hp = H_ws + cc*DS;
    #pragma unroll
    for (int s = 0; s < DS; s++) Hp[s] = h[s];
}

__global__ __launch_bounds__(256) void scan_combine(
    const float* __restrict__ sumdt_ws, const float* __restrict__ H_ws,
    const float* __restrict__ A_log, float* __restrict__ hinit_ws) {
    int g = blockIdx.x*256 + threadIdx.x;   // [0, Bv*DI*DS)
    int s = g & (DS-1);
    int bd = g >> 4;
    int d = bd % DI, b = bd / DI;
    float a = -__expf(A_log[d*DS + s]);
    float h = 0.f;
    for (int c = 0; c < NC; c++) {
        size_t cc = ((size_t)(b*NC + c))*DI + d;
        hinit_ws[cc*DS + s] = h;
        float sdt = sumdt_ws[cc];
        float Hv  = H_ws[cc*DS + s];
        h = __expf(a*sdt)*h + Hv;
    }
}

__global__ __launch_bounds__(256) void scan_final2(
    const float* __restrict__ xi, const float* __restrict__ xdbl,
    const float* __restrict__ xz, const float* __restrict__ A_log,
    const float* __restrict__ dtw, const float* __restrict__ dtb,
    const float* __restrict__ Dp, const float* __restrict__ hinit_ws,
    __hip_bfloat16* __restrict__ y) {
    __shared__ __attribute__((aligned(16))) float xb[CT*LROW];
    int tid = threadIdx.x;
    int bc = blockIdx.y;
    int b = bc / NC, c = bc % NC;
    size_t tok0 = (size_t)b*Lv + (size_t)c*CT;
    stage_xdbl(xb, xdbl, tok0, tid);
    __syncthreads();
    int d = blockIdx.x*256 + tid;
    if (d >= DI) return;

    float a[DS];
    const float* ap = A_log + (size_t)d*DS;
    #pragma unroll
    for (int s = 0; s < DS; s++) a[s] = -__expf(ap[s]);
    float w17[DTR];
    #pragma unroll
    for (int r = 0; r < DTR; r++) w17[r] = dtw[d*DTR + r];
    float dtbv = dtb[d];
    float Dv = Dp[d];

    float h[DS];
    const float* hp = hinit_ws + ((size_t)bc*DI + d)*DS;
    #pragma unroll
    for (int s = 0; s < DS; s++) h[s] = hp[s];

    #pragma unroll 2
    for (int t = 0; t < CT; t++) {
        const float* row = xb + t*LROW;
        size_t tok = tok0 + t;
        float u  = xi[tok*DI + d];
        float zv = xz[tok*N1p + DI + d];
        float acc = dtbv;
        #pragma unroll
        for (int r = 0; r < DTR; r++) acc = fmaf(row[r], w17[r], acc);
        float dtv = fmaxf(acc, 0.f) + log1pf(__expf(-fabsf(acc)));
        float du = dtv * u;
        float yv = 0.f;
        #pragma unroll
        for (int s = 0; s < DS; s++) {
            h[s] = __expf(dtv*a[s])*h[s] + du*row[20+s];
            yv = fmaf(h[s], row[36+s], yv);
        }
        yv = fmaf(u, Dv, yv);
        float g = zv / (1.f + __expf(-zv));
        y[tok*DIp + d] = __float2bfloat16(yv * g);
    }
}

extern "C" void kernel_launch(void* const* d_in, const int* in_sizes, int n_in,
                              void* d_out, int out_size, void* d_ws, size_t ws_size,
                              hipStream_t stream) {
    const float* fuse   = (const float*)d_in[0];
    const float* norm_w = (const float*)d_in[1];
    const float* in_w   = (const float*)d_in[2];
    const float* conv_w = (const float*)d_in[3];
    const float* conv_b = (const float*)d_in[4];
    const float* xp_w   = (const float*)d_in[5];
    const float* dt_w   = (const float*)d_in[6];
    const float* dt_b   = (const float*)d_in[7];
    const float* A_log  = (const float*)d_in[8];
    const float* D_par  = (const float*)d_in[9];
    const float* out_w  = (const float*)d_in[10];
    const float* fn_w   = (const float*)d_in[11];

    char* p = (char*)d_ws;
    auto alloc = [&](size_t bytes) { char* r = p; p += (bytes + 255) & ~(size_t)255; return r; };

    float*          x     = (float*)         alloc((size_t)TOK*DMp*4);
    __hip_bfloat16* xn    = (__hip_bfloat16*)alloc((size_t)TOK*DMp*2);
    float*          xz    = (float*)         alloc((size_t)TOK*N1p*4);
    float*          xi_f  = (float*)         alloc((size_t)TOK*DI*4);
    __hip_bfloat16* xi_b  = (__hip_bfloat16*)alloc((size_t)TOK*DIp*2);
    float*          xdbl  = (float*)         alloc((size_t)TOK*XDp*4);
    __hip_bfloat16* y     = (__hip_bfloat16*)alloc((size_t)TOK*DIp*2);
    float*          sumdt = (float*)         alloc((size_t)NCD*4);
    float*          Hws   = (float*)         alloc((size_t)NCD*DS*4);
    float*          hinit = (float*)         alloc((size_t)NCD*DS*4);
    __hip_bfloat16* W1b   = (__hip_bfloat16*)alloc((size_t)NL*N1p*DMp*2);
    __hip_bfloat16* W2b   = (__hip_bfloat16*)alloc((size_t)NL*XDp*DIp*2);
    __hip_bfloat16* W3b   = (__hip_bfloat16*)alloc((size_t)NL*N3p*DIp*2);

    {
        int t1 = NL*N1p*DMp, t2 = NL*XDp*DIp, t3 = NL*N3p*DIp;
        cvt_pad_kernel<<<(t1+255)/256, 256, 0, stream>>>(W1b, in_w, 2*DI, DM, N1p, DMp, t1);
        cvt_pad_kernel<<<(t2+255)/256, 256, 0, stream>>>(W2b, xp_w, DTR+2*DS, DI, XDp, DIp, t2);
        cvt_pad_kernel<<<(t3+255)/256, 256, 0, stream>>>(W3b, out_w, DM, DI, N3p, DIp, t3);
        int tz = 2*TOK*(DIp-DI);
        zero_pads_kernel<<<(tz+255)/256, 256, 0, stream>>>(xi_b, y);
    }

    for (int i = 0; i < NL; i++) {
        const __hip_bfloat16* w1 = W1b + (size_t)i*N1p*DMp;
        const __hip_bfloat16* w2 = W2b + (size_t)i*XDp*DIp;
        const __hip_bfloat16* w3 = W3b + (size_t)i*N3p*DIp;
        const float* cw   = conv_w + (size_t)i*DI*DC;
        const float* cb   = conv_b + (size_t)i*DI;
        const float* dtw  = dt_w   + (size_t)i*DI*DTR;
        const float* dtb  = dt_b   + (size_t)i*DI;
        const float* alog = A_log  + (size_t)i*DI*DS;
        const float* dp   = D_par  + (size_t)i*DI;
        const float* nw   = norm_w + (size_t)i*DM;
        const float* xcur = (i == 0) ? fuse : x;
        int ld_cur = (i == 0) ? DM : DMp;

        rmsnorm_kernel<<<TOK, 256, 0, stream>>>(xn, xcur, ld_cur, nw);
        gemm_bf16<<<dim3(N1p/128, TOK/128), 256, 0, stream>>>(
            xn, DMp, w1, DMp, xz, N1p, N1p, nullptr, 0, DMp);
        conv_silu_kernel<<<(TOK*DI + 255)/256, 256, 0, stream>>>(xi_f, xi_b, xz, cw, cb);
        gemm_bf16<<<dim3(XDp/128, TOK/128), 256, 0, stream>>>(
            xi_b, DIp, w2, DIp, xdbl, XDp, XDp, nullptr, 0, DIp);
        // chunked parallel scan (dt fused inline)
        scan_chunk2<<<dim3(3, NCB), 256, 0, stream>>>(xi_f, xdbl, alog, dtw, dtb, sumdt, Hws);
        scan_combine<<<(Bv*DI*DS)/256, 256, 0, stream>>>(sumdt, Hws, alog, hinit);
        scan_final2<<<dim3(3, NCB), 256, 0, stream>>>(xi_f, xdbl, xz, alog, dtw, dtb, dp, hinit, y);
        gemm_bf16<<<dim3(N3p/128, TOK/128), 256, 0, stream>>>(
            y, DIp, w3, DIp, x, DMp, DM, xcur, ld_cur, DIp);
    }

    final_kernel<<<TOK, 256, 0, stream>>>((float*)d_out, x, fuse, fn_w);
}